// Round 6
// baseline (261.630 us; speedup 1.0000x reference)
//
#include <hip/hip_runtime.h>
#include <hip/hip_bf16.h>

#define B_SZ 4
#define NHEADS 16
#define T_SZ 2048
#define DE 1024
#define DH 64
#define BH (B_SZ*NHEADS)
#define SCL 0.18033688011112042f  /* 0.125 * log2(e) */

typedef __attribute__((ext_vector_type(8))) short short8;   // 8 bf16 = 4 VGPRs
typedef __attribute__((ext_vector_type(4))) float float4v;
typedef __attribute__((ext_vector_type(2))) unsigned int uint2v;

__device__ __forceinline__ short f2bf(float f) {
    __hip_bfloat16 h = __float2bfloat16(f);
    return *reinterpret_cast<short*>(&h);
}
__device__ __forceinline__ unsigned int pack_bf2(float a, float b) {
    float2 f; f.x = a; f.y = b;
    __hip_bfloat162 h = __float22bfloat162_rn(f);
    return *reinterpret_cast<unsigned int*>(&h);
}
__device__ __forceinline__ float4v zero4() {
    float4v z = {0.f, 0.f, 0.f, 0.f};
    return z;
}
// XOR-swizzled stride-64 LDS tile. g is the LOGICAL 8-element column group;
// the physical slot is g ^ (row & 7). Use swz() for BOTH stores and loads
// with logical coordinates — never pre-XOR at the call site.
__device__ __forceinline__ int swz(int row, int g) {
    return row * 64 + (((g) ^ (row & 7)) << 3);
}

// ---- transpose+downcast: fp32 src[R][C] -> bf16 dst[C][R], batched over z ---
__global__ __launch_bounds__(256) void transpose_k(const float* __restrict__ src,
                                                   short* __restrict__ dst,
                                                   int R, int C) {
    __shared__ __align__(16) short tile[64 * 65];
    int c0 = blockIdx.x * 64, r0 = blockIdx.y * 64;
    src += (size_t)blockIdx.z * R * C;
    dst += (size_t)blockIdx.z * R * C;
    int tid = threadIdx.x;
#pragma unroll
    for (int it = 0; it < 16; ++it) {
        int idx = it * 256 + tid;
        int rr = idx >> 6, cc = idx & 63;
        tile[cc * 65 + rr] = f2bf(src[(size_t)(r0 + rr) * C + c0 + cc]);
    }
    __syncthreads();
#pragma unroll
    for (int it = 0; it < 16; ++it) {
        int idx = it * 256 + tid;
        int cc = idx >> 6, rr = idx & 63;
        dst[(size_t)(c0 + cc) * R + r0 + rr] = tile[cc * 65 + rr];
    }
}

// -------- QKV projection + q/k norm: M=256 x N=256 (4 heads of one n) --------
// XT: [b][t][d] bf16 ; WT: [n][h*64+e][d] bf16
// Qw (pre-scaled by SCL), Kw: [bh][t][e] ; Vt: [bh][e][t]
__global__ __launch_bounds__(512, 2) void qkv_k(const short* __restrict__ XT,
                                                const short* __restrict__ WT,
                                                short* __restrict__ Qw,
                                                short* __restrict__ Kw,
                                                short* __restrict__ Vt) {
    __shared__ __align__(16) short ldsA[256 * 64];   // 32 KB, swizzled
    __shared__ __align__(16) short ldsB[256 * 64];   // 32 KB, swizzled
    int b  = blockIdx.x >> 3;
    int t0 = (blockIdx.x & 7) * 256;
    int n  = blockIdx.y >> 2;
    int h0 = (blockIdx.y & 3) * 4;                   // 4 heads per block
    int tid = threadIdx.x, wave = tid >> 6, lane = tid & 63;
    int l15 = lane & 15, quad = lane >> 4;
    int wr = wave >> 1, wc = wave & 1;               // 4x2 wave grid

    const short* Arow = XT + ((size_t)b * T_SZ + t0) * DE;
    const short* Brow = WT + ((size_t)n * 1024 + h0 * 64) * DE;

    float4v acc[4][8];
#pragma unroll
    for (int mm = 0; mm < 4; ++mm)
#pragma unroll
        for (int j = 0; j < 8; ++j) acc[mm][j] = zero4();

    for (int k0 = 0; k0 < DE; k0 += 64) {
        __syncthreads();
#pragma unroll
        for (int it = 0; it < 4; ++it) {       // A,B: 256x64 = 2048 chunks of 8
            int idx = it * 512 + tid;
            int row = idx >> 3, g = idx & 7;
            *(short8*)&ldsA[swz(row, g)] =
                *(const short8*)&Arow[(size_t)row * DE + k0 + g * 8];
            *(short8*)&ldsB[swz(row, g)] =
                *(const short8*)&Brow[(size_t)row * DE + k0 + g * 8];
        }
        __syncthreads();
#pragma unroll
        for (int ks = 0; ks < 2; ++ks) {
            short8 af[4], bf[8];
#pragma unroll
            for (int mm = 0; mm < 4; ++mm)
                af[mm] = *(const short8*)&ldsA[swz(64 * wr + 16 * mm + l15, 4 * ks + quad)];
#pragma unroll
            for (int j = 0; j < 8; ++j)
                bf[j] = *(const short8*)&ldsB[swz(128 * wc + 16 * j + l15, 4 * ks + quad)];
#pragma unroll
            for (int mm = 0; mm < 4; ++mm)
#pragma unroll
                for (int j = 0; j < 8; ++j)
                    acc[mm][j] = __builtin_amdgcn_mfma_f32_16x16x32_bf16(af[mm], bf[j], acc[mm][j], 0, 0, 0);
        }
    }

    // epilogue: per 16-row subtile mm, per head-half jh (j = 4*jh .. 4*jh+3)
#pragma unroll
    for (int mm = 0; mm < 4; ++mm) {
        int tbase = t0 + 64 * wr + 16 * mm;
#pragma unroll
        for (int jh = 0; jh < 2; ++jh) {
            int h = h0 + 2 * wc + jh;
            int bh = b * NHEADS + h;
            if (n < 2) {
                float oscale = (n == 0) ? SCL : 1.0f;
                float mu[4], inv[4];
#pragma unroll
                for (int r = 0; r < 4; ++r) {
                    float s1 = 0.f, s2 = 0.f;
#pragma unroll
                    for (int jj = 0; jj < 4; ++jj) {
                        float v = acc[mm][4 * jh + jj][r];
                        s1 += v; s2 += v * v;
                    }
                    for (int sh = 1; sh < 16; sh <<= 1) {
                        s1 += __shfl_xor(s1, sh, 64);
                        s2 += __shfl_xor(s2, sh, 64);
                    }
                    mu[r] = s1 * (1.0f / 64.0f);
                    float var = (s2 - 64.0f * mu[r] * mu[r]) * (1.0f / 63.0f);
                    var = fmaxf(var, 0.0f);
                    inv[r] = oscale / (sqrtf(var) + 1e-5f);
                }
                short* dst = (n == 0 ? Qw : Kw) + (size_t)bh * T_SZ * DH;
#pragma unroll
                for (int r = 0; r < 4; ++r) {
                    int t = tbase + quad * 4 + r;
#pragma unroll
                    for (int jj = 0; jj < 4; ++jj) {
                        float v = (acc[mm][4 * jh + jj][r] - mu[r]) * inv[r];
                        dst[(size_t)t * DH + 16 * jj + l15] = f2bf(v);
                    }
                }
            } else {
#pragma unroll
                for (int r = 0; r < 4; ++r) {
                    int t = tbase + quad * 4 + r;
#pragma unroll
                    for (int jj = 0; jj < 4; ++jj) {
                        Vt[((size_t)bh * DH + 16 * jj + l15) * T_SZ + t] =
                            f2bf(acc[mm][4 * jh + jj][r]);
                    }
                }
            }
        }
    }
}

// ---------------- flash attention (64 q-rows/wave, MFMA l-sum) ---------------
// Qw (pre-scaled), Kw: [bh][t][e] ; Vt: [bh][e][t]  (bf16) ; out: fp32 [b][h*64+e][t]
// |q.k*SCL| <= 11.4 -> exp2 never overflows; no max subtraction needed.
__global__ __launch_bounds__(256, 3) void attn_k(const short* __restrict__ Qw,
                                                 const short* __restrict__ Kw,
                                                 const short* __restrict__ Vt,
                                                 float* __restrict__ out) {
    __shared__ __align__(16) char smem[53248];
    short* ldsK = (short*)smem;                 // [s][e] 64x64 swizzled (8 KB)
    short* ldsV = (short*)(smem + 8192);        // [e][s] 64x64 swizzled (8 KB)
    short* ldsP = (short*)(smem + 16384);       // per-wave [t][s] 64x72
    float* ldsO = (float*)smem;                 // epilogue alias: 2 x (64x68 fp32)

    int t0 = blockIdx.x * 256;
    int bh = blockIdx.y;
    int b = bh >> 4, h = bh & 15;
    int tid = threadIdx.x, wave = tid >> 6, lane = tid & 63;
    int l15 = lane & 15, quad = lane >> 4;
    int tw = t0 + 64 * wave;                    // this wave's 64 q-rows

    const short* Qp = Qw + (size_t)bh * T_SZ * DH;
    const short* Kp = Kw + (size_t)bh * T_SZ * DH;
    const short* Vp = Vt + (size_t)bh * DH * T_SZ;
    short* Pw = ldsP + wave * 64 * 72;

    short8 qf[4][2];   // B-operand: lane holds Q[t=tw+16tt+l15][e=ks*32+quad*8..+7]
#pragma unroll
    for (int tt = 0; tt < 4; ++tt)
#pragma unroll
        for (int ks = 0; ks < 2; ++ks)
            qf[tt][ks] = *(const short8*)&Qp[(size_t)(tw + 16 * tt + l15) * DH + ks * 32 + quad * 8];

    const short one_bf = (short)0x3F80;         // bf16 1.0
    short8 ones = {one_bf, one_bf, one_bf, one_bf, one_bf, one_bf, one_bf, one_bf};

    float4v o[4][4];   // [tt][j: e-subtile]
    float4v ol[4];     // row-sum accumulators (same C-layout rows as o)
#pragma unroll
    for (int tt = 0; tt < 4; ++tt) {
        ol[tt] = zero4();
#pragma unroll
        for (int j = 0; j < 4; ++j) o[tt][j] = zero4();
    }

    for (int s0 = 0; s0 < T_SZ; s0 += 64) {
        __syncthreads();
#pragma unroll
        for (int it = 0; it < 2; ++it) {   // stage K [s][e] and V^T [e][s], swizzled
            int idx = it * 256 + tid;
            int row = idx >> 3, g = idx & 7;
            *(short8*)&ldsK[swz(row, g)] = *(const short8*)&Kp[(size_t)(s0 + row) * DH + g * 8];
            *(short8*)&ldsV[swz(row, g)] = *(const short8*)&Vp[(size_t)row * T_SZ + s0 + g * 8];
        }
        __syncthreads();

        // S^T = K.Q^T: C[row=s_local][col=t_local]; lane's 4 regs = 4 consecutive s
#pragma unroll
        for (int j = 0; j < 4; ++j) {
            short8 k0 = *(const short8*)&ldsK[swz(16 * j + l15, quad)];
            short8 k1 = *(const short8*)&ldsK[swz(16 * j + l15, 4 + quad)];
#pragma unroll
            for (int tt = 0; tt < 4; ++tt) {
                float4v z = zero4();
                z = __builtin_amdgcn_mfma_f32_16x16x32_bf16(k0, qf[tt][0], z, 0, 0, 0);
                z = __builtin_amdgcn_mfma_f32_16x16x32_bf16(k1, qf[tt][1], z, 0, 0, 0);
                float p0 = __builtin_amdgcn_exp2f(z[0]);
                float p1 = __builtin_amdgcn_exp2f(z[1]);
                float p2 = __builtin_amdgcn_exp2f(z[2]);
                float p3 = __builtin_amdgcn_exp2f(z[3]);
                uint2v u = { pack_bf2(p0, p1), pack_bf2(p2, p3) };
                // P[t=16tt+l15][s=16j+quad*4 .. +3] — this wave's private region
                *(uint2v*)&Pw[(16 * tt + l15) * 72 + 16 * j + quad * 4] = u;
            }
        }

        // PV: A = P[t][s], B = V^T[e][s]; l-sum via ones-B MFMA (same A frags)
        short8 pf[4][2];
#pragma unroll
        for (int tt = 0; tt < 4; ++tt) {
            pf[tt][0] = *(const short8*)&Pw[(16 * tt + l15) * 72 + quad * 8];
            pf[tt][1] = *(const short8*)&Pw[(16 * tt + l15) * 72 + 32 + quad * 8];
            ol[tt] = __builtin_amdgcn_mfma_f32_16x16x32_bf16(pf[tt][0], ones, ol[tt], 0, 0, 0);
            ol[tt] = __builtin_amdgcn_mfma_f32_16x16x32_bf16(pf[tt][1], ones, ol[tt], 0, 0, 0);
        }
#pragma unroll
        for (int j = 0; j < 4; ++j) {
            short8 v0 = *(const short8*)&ldsV[swz(16 * j + l15, quad)];
            short8 v1 = *(const short8*)&ldsV[swz(16 * j + l15, 4 + quad)];
#pragma unroll
            for (int tt = 0; tt < 4; ++tt) {
                o[tt][j] = __builtin_amdgcn_mfma_f32_16x16x32_bf16(pf[tt][0], v0, o[tt][j], 0, 0, 0);
                o[tt][j] = __builtin_amdgcn_mfma_f32_16x16x32_bf16(pf[tt][1], v1, o[tt][j], 0, 0, 0);
            }
        }
    }

    // rinv: ol[tt][r] is l for t = tw+16tt+quad*4+r — same lane-mapping as o[tt][j][r]
    float4v rinv[4];
#pragma unroll
    for (int tt = 0; tt < 4; ++tt)
#pragma unroll
        for (int r = 0; r < 4; ++r)
            rinv[tt][r] = 1.0f / ol[tt][r];

    // epilogue: normalize, transpose via LDS (2 phases x 2 waves), float4 stores
#pragma unroll
    for (int ph = 0; ph < 2; ++ph) {
        __syncthreads();
        if ((wave >> 1) == ph) {
            float* Ow = ldsO + (wave & 1) * (64 * 68);
#pragma unroll
            for (int tt = 0; tt < 4; ++tt)
#pragma unroll
                for (int j = 0; j < 4; ++j) {
                    float4v ov = o[tt][j] * rinv[tt];
                    // O[t = tw+16tt+quad*4+r][e = 16j+l15]
                    *(float4v*)&Ow[(16 * j + l15) * 68 + 16 * tt + quad * 4] = ov;
                }
        }
        __syncthreads();
#pragma unroll
        for (int it = 0; it < 8; ++it) {
            int idx = it * 256 + tid;          // 2048 float4 = 2 regions x 64e x 64t
            int reg = idx >> 10;
            int rid = idx & 1023;
            int e = rid >> 4, t4 = (rid & 15) * 4;
            *(float4v*)&out[((size_t)(b * DE + h * DH + e)) * T_SZ + t0 + 128 * ph + 64 * reg + t4] =
                *(const float4v*)&ldsO[reg * (64 * 68) + e * 68 + t4];
        }
    }
}

extern "C" void kernel_launch(void* const* d_in, const int* in_sizes, int n_in,
                              void* d_out, int out_size, void* d_ws, size_t ws_size,
                              hipStream_t stream) {
    const float* x = (const float*)d_in[0];   // fp32 [B][D][T]
    const float* w = (const float*)d_in[1];   // fp32 [3][H][D][dh]
    float* out = (float*)d_out;               // fp32 [B][D][T]
    char* ws = (char*)d_ws;

    const size_t XT_BYTES = (size_t)B_SZ * T_SZ * DE * 2;       // 16.8 MB (bf16)
    const size_t WT_BYTES = (size_t)3 * NHEADS * DH * DE * 2;   // 6.3 MB
    const size_t QKV_BYTES = (size_t)BH * T_SZ * DH * 2;        // 16.8 MB each

    short* XT = (short*)(ws);
    short* WT = (short*)(ws + XT_BYTES);
    short* Qw = (short*)(ws + XT_BYTES + WT_BYTES);
    short* Kw = (short*)(ws + XT_BYTES + WT_BYTES + QKV_BYTES);
    short* Vt = (short*)(ws + XT_BYTES + WT_BYTES + 2 * QKV_BYTES);

    // x: per-b fp32 [D][T] -> bf16 XT [T][D]
    transpose_k<<<dim3(T_SZ / 64, DE / 64, B_SZ), 256, 0, stream>>>(x, XT, DE, T_SZ);
    // w: per-nh fp32 [D][dh] -> bf16 WT [nh][e][D]
    transpose_k<<<dim3(1, DE / 64, 3 * NHEADS), 256, 0, stream>>>(w, WT, DE, DH);
    qkv_k<<<dim3(32, 12), 512, 0, stream>>>(XT, WT, Qw, Kw, Vt);
    attn_k<<<dim3(T_SZ / 256, BH), 256, 0, stream>>>(Qw, Kw, Vt, out);
}

// Round 7
// 238.376 us; speedup vs baseline: 1.0976x; 1.0976x over previous
//
#include <hip/hip_runtime.h>
#include <hip/hip_bf16.h>

#define B_SZ 4
#define NHEADS 16
#define T_SZ 2048
#define DE 1024
#define DH 64
#define BH (B_SZ*NHEADS)
#define SCL 0.18033688011112042f  /* 0.125 * log2(e) */

typedef __attribute__((ext_vector_type(8))) short short8;   // 8 bf16 = 4 VGPRs
typedef __attribute__((ext_vector_type(4))) float float4v;
typedef __attribute__((ext_vector_type(2))) unsigned int uint2v;

__device__ __forceinline__ short f2bf(float f) {
    __hip_bfloat16 h = __float2bfloat16(f);
    return *reinterpret_cast<short*>(&h);
}
__device__ __forceinline__ unsigned int pack_bf2(float a, float b) {
    float2 f; f.x = a; f.y = b;
    __hip_bfloat162 h = __float22bfloat162_rn(f);
    return *reinterpret_cast<unsigned int*>(&h);
}
__device__ __forceinline__ float4v zero4() {
    float4v z = {0.f, 0.f, 0.f, 0.f};
    return z;
}
// XOR-swizzled stride-64 LDS tile. g is the LOGICAL 8-element column group;
// physical slot is g ^ (row & 7). Pass logical coords to BOTH stores and loads.
__device__ __forceinline__ int swz(int row, int g) {
    return row * 64 + (((g) ^ (row & 7)) << 3);
}

// ---- transpose+downcast: fp32 src[R][C] -> bf16 dst[C][R], batched over z ---
__global__ __launch_bounds__(256) void transpose_k(const float* __restrict__ src,
                                                   short* __restrict__ dst,
                                                   int R, int C) {
    __shared__ __align__(16) short tile[64 * 65];
    int c0 = blockIdx.x * 64, r0 = blockIdx.y * 64;
    src += (size_t)blockIdx.z * R * C;
    dst += (size_t)blockIdx.z * R * C;
    int tid = threadIdx.x;
#pragma unroll
    for (int it = 0; it < 16; ++it) {
        int idx = it * 256 + tid;
        int rr = idx >> 6, cc = idx & 63;
        tile[cc * 65 + rr] = f2bf(src[(size_t)(r0 + rr) * C + c0 + cc]);
    }
    __syncthreads();
#pragma unroll
    for (int it = 0; it < 16; ++it) {
        int idx = it * 256 + tid;
        int cc = idx >> 6, rr = idx & 63;
        dst[(size_t)(c0 + cc) * R + r0 + rr] = tile[cc * 65 + rr];
    }
}

// -------- QKV projection + q/k norm: M=128 x N=256 (4 heads of one n) --------
// 768 blocks = 3 balanced rounds of 256 CUs at 2-resident.
// XT: [b][t][d] bf16 ; WT: [n][h*64+e][d] bf16
// Qw (pre-scaled by SCL), Kw: [bh][t][e] ; Vt: [bh][e][t]
__global__ __launch_bounds__(256, 2) void qkv_k(const short* __restrict__ XT,
                                                const short* __restrict__ WT,
                                                short* __restrict__ Qw,
                                                short* __restrict__ Kw,
                                                short* __restrict__ Vt) {
    __shared__ __align__(16) short ldsA[128 * 64];   // 16 KB, swizzled
    __shared__ __align__(16) short ldsB[256 * 64];   // 32 KB, swizzled
    int b  = blockIdx.x >> 4;                        // grid.x = 64: same-A blocks
    int t0 = (blockIdx.x & 15) * 128;                //   share XCD (x mod 8 const in y)
    int n  = blockIdx.y >> 2;
    int h0 = (blockIdx.y & 3) * 4;                   // 4 heads per block
    int tid = threadIdx.x, wave = tid >> 6, lane = tid & 63;
    int l15 = lane & 15, quad = lane >> 4;
    int wr = wave >> 1, wc = wave & 1;               // 2x2 wave grid

    const short* Arow = XT + ((size_t)b * T_SZ + t0) * DE;
    const short* Brow = WT + ((size_t)n * 1024 + h0 * 64) * DE;

    float4v acc[4][8];
#pragma unroll
    for (int mm = 0; mm < 4; ++mm)
#pragma unroll
        for (int j = 0; j < 8; ++j) acc[mm][j] = zero4();

    for (int k0 = 0; k0 < DE; k0 += 64) {
        __syncthreads();
#pragma unroll
        for (int it = 0; it < 4; ++it) {       // A: 128x64 = 1024 chunks of 8
            int idx = it * 256 + tid;
            int row = idx >> 3, g = idx & 7;
            *(short8*)&ldsA[swz(row, g)] =
                *(const short8*)&Arow[(size_t)row * DE + k0 + g * 8];
        }
#pragma unroll
        for (int it = 0; it < 8; ++it) {       // B: 256x64 = 2048 chunks of 8
            int idx = it * 256 + tid;
            int row = idx >> 3, g = idx & 7;
            *(short8*)&ldsB[swz(row, g)] =
                *(const short8*)&Brow[(size_t)row * DE + k0 + g * 8];
        }
        __syncthreads();
#pragma unroll
        for (int ks = 0; ks < 2; ++ks) {
            short8 af[4], bf[8];
#pragma unroll
            for (int mm = 0; mm < 4; ++mm)
                af[mm] = *(const short8*)&ldsA[swz(64 * wr + 16 * mm + l15, 4 * ks + quad)];
#pragma unroll
            for (int j = 0; j < 8; ++j)
                bf[j] = *(const short8*)&ldsB[swz(128 * wc + 16 * j + l15, 4 * ks + quad)];
#pragma unroll
            for (int mm = 0; mm < 4; ++mm)
#pragma unroll
                for (int j = 0; j < 8; ++j)
                    acc[mm][j] = __builtin_amdgcn_mfma_f32_16x16x32_bf16(af[mm], bf[j], acc[mm][j], 0, 0, 0);
        }
    }

    // epilogue: per 16-row subtile mm, per head-half jh (j = 4*jh .. 4*jh+3)
#pragma unroll
    for (int mm = 0; mm < 4; ++mm) {
        int tbase = t0 + 64 * wr + 16 * mm;
#pragma unroll
        for (int jh = 0; jh < 2; ++jh) {
            int h = h0 + 2 * wc + jh;
            int bh = b * NHEADS + h;
            if (n < 2) {
                float oscale = (n == 0) ? SCL : 1.0f;
                float mu[4], inv[4];
#pragma unroll
                for (int r = 0; r < 4; ++r) {
                    float s1 = 0.f, s2 = 0.f;
#pragma unroll
                    for (int jj = 0; jj < 4; ++jj) {
                        float v = acc[mm][4 * jh + jj][r];
                        s1 += v; s2 += v * v;
                    }
                    for (int sh = 1; sh < 16; sh <<= 1) {
                        s1 += __shfl_xor(s1, sh, 64);
                        s2 += __shfl_xor(s2, sh, 64);
                    }
                    mu[r] = s1 * (1.0f / 64.0f);
                    float var = (s2 - 64.0f * mu[r] * mu[r]) * (1.0f / 63.0f);
                    var = fmaxf(var, 0.0f);
                    inv[r] = oscale / (sqrtf(var) + 1e-5f);
                }
                short* dst = (n == 0 ? Qw : Kw) + (size_t)bh * T_SZ * DH;
#pragma unroll
                for (int r = 0; r < 4; ++r) {
                    int t = tbase + quad * 4 + r;
#pragma unroll
                    for (int jj = 0; jj < 4; ++jj) {
                        float v = (acc[mm][4 * jh + jj][r] - mu[r]) * inv[r];
                        dst[(size_t)t * DH + 16 * jj + l15] = f2bf(v);
                    }
                }
            } else {
#pragma unroll
                for (int r = 0; r < 4; ++r) {
                    int t = tbase + quad * 4 + r;
#pragma unroll
                    for (int jj = 0; jj < 4; ++jj) {
                        Vt[((size_t)bh * DH + 16 * jj + l15) * T_SZ + t] =
                            f2bf(acc[mm][4 * jh + jj][r]);
                    }
                }
            }
        }
    }
}

// ---------------- flash attention (64 q-rows/wave, MFMA l-sum) ---------------
// Grid (x=bh, y=tq): the 8 blocks sharing one bh's K/V land on one XCD.
// Qw (pre-scaled), Kw: [bh][t][e] ; Vt: [bh][e][t]  (bf16) ; out: fp32 [b][h*64+e][t]
// |q.k*SCL| <= 11.4 -> exp2 never overflows; no max subtraction needed.
__global__ __launch_bounds__(256, 3) void attn_k(const short* __restrict__ Qw,
                                                 const short* __restrict__ Kw,
                                                 const short* __restrict__ Vt,
                                                 float* __restrict__ out) {
    __shared__ __align__(16) char smem[53248];
    short* ldsK = (short*)smem;                 // [s][e] 64x64 swizzled (8 KB)
    short* ldsV = (short*)(smem + 8192);        // [e][s] 64x64 swizzled (8 KB)
    short* ldsP = (short*)(smem + 16384);       // per-wave [t][s] 64x72
    float* ldsO = (float*)smem;                 // epilogue alias: 2 x (64x68 fp32)

    int bh = blockIdx.x;
    int t0 = blockIdx.y * 256;
    int b = bh >> 4, h = bh & 15;
    int tid = threadIdx.x, wave = tid >> 6, lane = tid & 63;
    int l15 = lane & 15, quad = lane >> 4;
    int tw = t0 + 64 * wave;                    // this wave's 64 q-rows

    const short* Qp = Qw + (size_t)bh * T_SZ * DH;
    const short* Kp = Kw + (size_t)bh * T_SZ * DH;
    const short* Vp = Vt + (size_t)bh * DH * T_SZ;
    short* Pw = ldsP + wave * 64 * 72;

    short8 qf[4][2];   // B-operand: lane holds Q[t=tw+16tt+l15][e=ks*32+quad*8..+7]
#pragma unroll
    for (int tt = 0; tt < 4; ++tt)
#pragma unroll
        for (int ks = 0; ks < 2; ++ks)
            qf[tt][ks] = *(const short8*)&Qp[(size_t)(tw + 16 * tt + l15) * DH + ks * 32 + quad * 8];

    const short one_bf = (short)0x3F80;         // bf16 1.0
    short8 ones = {one_bf, one_bf, one_bf, one_bf, one_bf, one_bf, one_bf, one_bf};

    float4v o[4][4];   // [tt][j: e-subtile]
    float4v ol[4];     // row-sum accumulators (same C-layout rows as o)
#pragma unroll
    for (int tt = 0; tt < 4; ++tt) {
        ol[tt] = zero4();
#pragma unroll
        for (int j = 0; j < 4; ++j) o[tt][j] = zero4();
    }

    for (int s0 = 0; s0 < T_SZ; s0 += 64) {
        __syncthreads();
#pragma unroll
        for (int it = 0; it < 2; ++it) {   // stage K [s][e] and V^T [e][s], swizzled
            int idx = it * 256 + tid;
            int row = idx >> 3, g = idx & 7;
            *(short8*)&ldsK[swz(row, g)] = *(const short8*)&Kp[(size_t)(s0 + row) * DH + g * 8];
            *(short8*)&ldsV[swz(row, g)] = *(const short8*)&Vp[(size_t)row * T_SZ + s0 + g * 8];
        }
        __syncthreads();

        // S^T = K.Q^T: C[row=s_local][col=t_local]; lane's 4 regs = 4 consecutive s
#pragma unroll
        for (int j = 0; j < 4; ++j) {
            short8 k0 = *(const short8*)&ldsK[swz(16 * j + l15, quad)];
            short8 k1 = *(const short8*)&ldsK[swz(16 * j + l15, 4 + quad)];
#pragma unroll
            for (int tt = 0; tt < 4; ++tt) {
                float4v z = zero4();
                z = __builtin_amdgcn_mfma_f32_16x16x32_bf16(k0, qf[tt][0], z, 0, 0, 0);
                z = __builtin_amdgcn_mfma_f32_16x16x32_bf16(k1, qf[tt][1], z, 0, 0, 0);
                float p0 = __builtin_amdgcn_exp2f(z[0]);
                float p1 = __builtin_amdgcn_exp2f(z[1]);
                float p2 = __builtin_amdgcn_exp2f(z[2]);
                float p3 = __builtin_amdgcn_exp2f(z[3]);
                uint2v u = { pack_bf2(p0, p1), pack_bf2(p2, p3) };
                // P[t=16tt+l15][s=16j+quad*4 .. +3] — this wave's private region
                *(uint2v*)&Pw[(16 * tt + l15) * 72 + 16 * j + quad * 4] = u;
            }
        }

        // PV: A = P[t][s], B = V^T[e][s]; l-sum via ones-B MFMA (same A frags)
        short8 pf[4][2];
#pragma unroll
        for (int tt = 0; tt < 4; ++tt) {
            pf[tt][0] = *(const short8*)&Pw[(16 * tt + l15) * 72 + quad * 8];
            pf[tt][1] = *(const short8*)&Pw[(16 * tt + l15) * 72 + 32 + quad * 8];
            ol[tt] = __builtin_amdgcn_mfma_f32_16x16x32_bf16(pf[tt][0], ones, ol[tt], 0, 0, 0);
            ol[tt] = __builtin_amdgcn_mfma_f32_16x16x32_bf16(pf[tt][1], ones, ol[tt], 0, 0, 0);
        }
#pragma unroll
        for (int j = 0; j < 4; ++j) {
            short8 v0 = *(const short8*)&ldsV[swz(16 * j + l15, quad)];
            short8 v1 = *(const short8*)&ldsV[swz(16 * j + l15, 4 + quad)];
#pragma unroll
            for (int tt = 0; tt < 4; ++tt) {
                o[tt][j] = __builtin_amdgcn_mfma_f32_16x16x32_bf16(pf[tt][0], v0, o[tt][j], 0, 0, 0);
                o[tt][j] = __builtin_amdgcn_mfma_f32_16x16x32_bf16(pf[tt][1], v1, o[tt][j], 0, 0, 0);
            }
        }
    }

    // rinv: ol[tt][r] is l for t = tw+16tt+quad*4+r — same lane-mapping as o[tt][j][r]
    float4v rinv[4];
#pragma unroll
    for (int tt = 0; tt < 4; ++tt)
#pragma unroll
        for (int r = 0; r < 4; ++r)
            rinv[tt][r] = 1.0f / ol[tt][r];

    // epilogue: normalize, transpose via LDS (2 phases x 2 waves), float4 stores
#pragma unroll
    for (int ph = 0; ph < 2; ++ph) {
        __syncthreads();
        if ((wave >> 1) == ph) {
            float* Ow = ldsO + (wave & 1) * (64 * 68);
#pragma unroll
            for (int tt = 0; tt < 4; ++tt)
#pragma unroll
                for (int j = 0; j < 4; ++j) {
                    float4v ov = o[tt][j] * rinv[tt];
                    // O[t = tw+16tt+quad*4+r][e = 16j+l15]
                    *(float4v*)&Ow[(16 * j + l15) * 68 + 16 * tt + quad * 4] = ov;
                }
        }
        __syncthreads();
#pragma unroll
        for (int it = 0; it < 8; ++it) {
            int idx = it * 256 + tid;          // 2048 float4 = 2 regions x 64e x 64t
            int reg = idx >> 10;
            int rid = idx & 1023;
            int e = rid >> 4, t4 = (rid & 15) * 4;
            *(float4v*)&out[((size_t)(b * DE + h * DH + e)) * T_SZ + t0 + 128 * ph + 64 * reg + t4] =
                *(const float4v*)&ldsO[reg * (64 * 68) + e * 68 + t4];
        }
    }
}

extern "C" void kernel_launch(void* const* d_in, const int* in_sizes, int n_in,
                              void* d_out, int out_size, void* d_ws, size_t ws_size,
                              hipStream_t stream) {
    const float* x = (const float*)d_in[0];   // fp32 [B][D][T]
    const float* w = (const float*)d_in[1];   // fp32 [3][H][D][dh]
    float* out = (float*)d_out;               // fp32 [B][D][T]
    char* ws = (char*)d_ws;

    const size_t XT_BYTES = (size_t)B_SZ * T_SZ * DE * 2;       // 16.8 MB (bf16)
    const size_t WT_BYTES = (size_t)3 * NHEADS * DH * DE * 2;   // 6.3 MB
    const size_t QKV_BYTES = (size_t)BH * T_SZ * DH * 2;        // 16.8 MB each

    short* XT = (short*)(ws);
    short* WT = (short*)(ws + XT_BYTES);
    short* Qw = (short*)(ws + XT_BYTES + WT_BYTES);
    short* Kw = (short*)(ws + XT_BYTES + WT_BYTES + QKV_BYTES);
    short* Vt = (short*)(ws + XT_BYTES + WT_BYTES + 2 * QKV_BYTES);

    // x: per-b fp32 [D][T] -> bf16 XT [T][D]
    transpose_k<<<dim3(T_SZ / 64, DE / 64, B_SZ), 256, 0, stream>>>(x, XT, DE, T_SZ);
    // w: per-nh fp32 [D][dh] -> bf16 WT [nh][e][D]
    transpose_k<<<dim3(1, DE / 64, 3 * NHEADS), 256, 0, stream>>>(w, WT, DE, DH);
    qkv_k<<<dim3(64, 12), 256, 0, stream>>>(XT, WT, Qw, Kw, Vt);
    attn_k<<<dim3(BH, T_SZ / 256), 256, 0, stream>>>(Qw, Kw, Vt, out);
}